// Round 10
// baseline (651.706 us; speedup 1.0000x reference)
//
#include <hip/hip_runtime.h>
#include <hip/hip_bf16.h>
#include <math.h>

#define NROWS 8192
#define DIM   1024
#define CAP   256
#define MARGIN 120.0f

using f16x8 = __attribute__((ext_vector_type(8))) _Float16;
using f32x4 = __attribute__((ext_vector_type(4))) float;
typedef unsigned short u16;
typedef unsigned int   u32;

#define AS1 __attribute__((address_space(1)))
#define AS3 __attribute__((address_space(3)))

// ---------------- split fp32 array (len % 1024 == 0) into hi/lo fp16 planes ----
__global__ __launch_bounds__(256) void split2h(const float* __restrict__ X,
                                               u16* __restrict__ H,
                                               u16* __restrict__ L) {
    const int idx = (blockIdx.x * 256 + threadIdx.x) * 4;
    float4 x = *(const float4*)&X[idx];
    float c[4] = {x.x, x.y, x.z, x.w};
    u16 h[4], l[4];
#pragma unroll
    for (int i = 0; i < 4; ++i) {
        _Float16 hh = (_Float16)c[i];
        float r = c[i] - (float)hh;
        _Float16 ll = (_Float16)r;
        h[i] = *(u16*)&hh; l[i] = *(u16*)&ll;
    }
    *(ushort4*)&H[idx] = make_ushort4(h[0], h[1], h[2], h[3]);
    *(ushort4*)&L[idx] = make_ushort4(l[0], l[1], l[2], l[3]);
}

// ---------------- transpose Wv, keep hi fp16 plane: Wvth[c][d] = f16(Wv[d][c]) -
__global__ __launch_bounds__(256) void split_wvt(const float* __restrict__ W,
                                                 u16* __restrict__ H) {
    __shared__ float t[64][65];
    const int k0 = blockIdx.x * 64, n0 = blockIdx.y * 64;
    const int c = threadIdx.x & 63, r4 = threadIdx.x >> 6;
#pragma unroll
    for (int i = 0; i < 16; ++i) {
        int k = r4 + i * 4;
        t[k][c] = W[(size_t)(k0 + k) * DIM + n0 + c];
    }
    __syncthreads();
#pragma unroll
    for (int i = 0; i < 16; ++i) {
        int n = r4 + i * 4;
        _Float16 hb = (_Float16)t[c][n];
        H[(n0 + n) * DIM + k0 + c] = *(u16*)&hb;
    }
}

// ---------------- wave-private, barrier-free 128x128 NT fp16 GEMM engine -------
// R9 POST-MORTEM FIX: without __syncthreads, the compiler inserts NO vmcnt wait
// between global_load_lds and the dependent ds_read (the dependency is through
// LDS memory, not registers) -> R9 read stale LDS garbage -> NaN acc -> zero
// candidates -> all-zero output (absmax matched the round-0 stub exactly).
// Explicit `s_waitcnt vmcnt(8)` (memory-clobber asm) after issuing the next
// buffer's 8 loads drains exactly the current buffer's 8 (m135 semantics:
// waits for outstanding-N oldest) while the prefetch stays in flight across
// the whole compute body — the AITER/hipBLASLt fine-grained-vmcnt pattern.
// Waves stay barrier-free and slip independently (the R8 convoy lesson).
// XOR chunk swizzle: LDS slot s of row r holds global chunk s ^ ((r>>1)&3);
// read side uses slot quad ^ ((r16>>1)&3). Bank enumeration: each 8-lane
// cohort's ds_read_b128 covers all 32 banks exactly once -> conflict-free
// (R7/R8 layout was 8 lanes/bank, 1.678e7 conflicts).
// WAR safety (iter i DMA overwrites buffer read at i-1): the overwrite trails
// those ds_reads by a full iteration (~300 cyc) vs <120 cyc read sampling.
template<int NP>
__device__ __forceinline__ void gemm_wp(const u16* const (&Ap)[NP],
                                        const u16* const (&Bp)[NP],
                                        int row0, int col0,
                                        f32x4 (&acc)[4][4],
                                        short (&Ls)[2][4096]) {
    const int tid  = threadIdx.x;
    const int lane = tid & 63;
    const int w    = tid >> 6;
    const int wy = w >> 1, wx = w & 1;
    const int quad = lane >> 4, r16 = lane & 15;

    // staging map: instr t covers rows [t*16, t*16+16) of this wave's 64-row
    // half; lane l -> row t*16 + (l>>2), global chunk (l&3)^((l>>3)&3).
    // ((row)>>1)&3 == (l>>3)&3 because t*16>>1 is a multiple of 8.
    const int    srow   = lane >> 2;
    const int    schunk = ((lane & 3) ^ ((lane >> 3) & 3)) * 8;
    const size_t gA = (size_t)(row0 + wy * 64 + srow) * DIM + schunk;
    const size_t gB = (size_t)(col0 + wx * 64 + srow) * DIM + schunk;

    auto issue = [&](const u16* A, const u16* B, size_t ko, int buf) {
#pragma unroll
        for (int t = 0; t < 4; ++t)
            __builtin_amdgcn_global_load_lds((const AS1 u32*)(A + gA + (size_t)t * 16 * DIM + ko),
                                             (AS3 u32*)&Ls[buf][t * 512], 16, 0, 0);
#pragma unroll
        for (int t = 0; t < 4; ++t)
            __builtin_amdgcn_global_load_lds((const AS1 u32*)(B + gB + (size_t)t * 16 * DIM + ko),
                                             (AS3 u32*)&Ls[buf][2048 + t * 512], 16, 0, 0);
    };

    issue(Ap[0], Bp[0], 0, 0);             // preload product 0, k-chunk 0

    int pp = 0;
#pragma unroll
    for (int p = 0; p < NP; ++p) {
        const u16* A  = Ap[p];
        const u16* B  = Bp[p];
        const u16* An = (p + 1 < NP) ? Ap[p + 1] : A;
        const u16* Bn = (p + 1 < NP) ? Bp[p + 1] : B;
        const bool more = (p + 1 < NP);
        for (int i = 0; i < 32; ++i) {     // BK=32, K/32 iterations
            const int cur = pp, nxt = pp ^ 1;
            // issue prefetch FIRST, then wait for only the 8 oldest loads
            // (current buffer); the 8 new ones fly across this iteration.
            if (i < 31) {
                issue(A, B, (size_t)(i + 1) * 32, nxt);
                asm volatile("s_waitcnt vmcnt(8)" ::: "memory");
            } else if (more) {
                issue(An, Bn, 0, nxt);
                asm volatile("s_waitcnt vmcnt(8)" ::: "memory");
            } else {
                asm volatile("s_waitcnt vmcnt(0)" ::: "memory");
            }
            const int swz = (quad ^ ((r16 >> 1) & 3)) * 8;
            f16x8 af[4], bfr[4];
#pragma unroll
            for (int m = 0; m < 4; ++m)
                af[m] = *(const f16x8*)&Ls[cur][(m * 16 + r16) * 32 + swz];
#pragma unroll
            for (int n = 0; n < 4; ++n)
                bfr[n] = *(const f16x8*)&Ls[cur][2048 + (n * 16 + r16) * 32 + swz];
#pragma unroll
            for (int m = 0; m < 4; ++m)
#pragma unroll
                for (int n = 0; n < 4; ++n)
                    acc[m][n] = __builtin_amdgcn_mfma_f32_16x16x32_f16(af[m], bfr[n], acc[m][n], 0, 0, 0);
            pp ^= 1;
        }
    }
}

// ---------------- Gt = Wk @ Wq^T (fp32 out, Gt[c][d] = (Wq Wk^T)[d][c]) --------
__global__ __launch_bounds__(256) void g_gemm(const u16* __restrict__ Wkh, const u16* __restrict__ Wkl,
                                              const u16* __restrict__ Wqh, const u16* __restrict__ Wql,
                                              float* __restrict__ Gt) {
    __shared__ short Ls[4][2][4096];       // 64 KB: per-wave private dbuf
    const int tid = threadIdx.x, w = tid >> 6, lane = tid & 63;
    const int wy = w >> 1, wx = w & 1, quad = lane >> 4, r16 = lane & 15;
    const int row0 = blockIdx.y * 128, col0 = blockIdx.x * 128;
    const u16* const Ap[3] = { Wkl, Wkh, Wkh };   // lh, hl, hh (small -> large)
    const u16* const Bp[3] = { Wqh, Wql, Wqh };
    f32x4 acc[4][4] = {};
    gemm_wp<3>(Ap, Bp, row0, col0, acc, Ls[w]);
#pragma unroll
    for (int m = 0; m < 4; ++m)
#pragma unroll
        for (int n = 0; n < 4; ++n)
#pragma unroll
            for (int reg = 0; reg < 4; ++reg) {
                const int row = row0 + wy * 64 + m * 16 + quad * 4 + reg;
                const int col = col0 + wx * 64 + n * 16 + r16;
                Gt[row * DIM + col] = acc[m][n][reg];
            }
}

// ---------------- id<512: Y = X@G (fp32+fp16) ; id>=512: Vh = Xh@Wvt_h ---------
// id%8 == rowt%8: XCD round-robin pins each XCD's A-row-tiles in its L2 (R7).
__global__ __launch_bounds__(256) void yv_gemm(const u16* __restrict__ Xh, const u16* __restrict__ Xl,
                                               const u16* __restrict__ Gth, const u16* __restrict__ Gtl,
                                               const u16* __restrict__ Wvth,
                                               float* __restrict__ Y, u16* __restrict__ Yh, u16* __restrict__ Vh) {
    __shared__ short Ls[4][2][4096];
    const int tid = threadIdx.x, w = tid >> 6, lane = tid & 63;
    const int wy = w >> 1, wx = w & 1, quad = lane >> 4, r16 = lane & 15;
    const int id = blockIdx.x;
    const int z = id >> 9;
    const int within = id & 511;
    const int colt = within >> 6;          // 0..7
    const int rowt = within & 63;          // 0..63
    const int row0 = rowt * 128, col0 = colt * 128;
    f32x4 acc[4][4] = {};
    if (z == 0) {
        const u16* const Ap[3] = { Xl,  Xh,  Xh  };   // lh, hl, hh
        const u16* const Bp[3] = { Gth, Gtl, Gth };
        gemm_wp<3>(Ap, Bp, row0, col0, acc, Ls[w]);
#pragma unroll
        for (int m = 0; m < 4; ++m)
#pragma unroll
            for (int n = 0; n < 4; ++n)
#pragma unroll
                for (int reg = 0; reg < 4; ++reg) {
                    const int row = row0 + wy * 64 + m * 16 + quad * 4 + reg;
                    const int col = col0 + wx * 64 + n * 16 + r16;
                    float v = acc[m][n][reg];
                    Y[row * DIM + col] = v;
                    _Float16 hb = (_Float16)v;
                    Yh[row * DIM + col] = *(u16*)&hb;
                }
    } else {
        const u16* const Ap[1] = { Xh };
        const u16* const Bp[1] = { Wvth };
        gemm_wp<1>(Ap, Bp, row0, col0, acc, Ls[w]);
#pragma unroll
        for (int m = 0; m < 4; ++m)
#pragma unroll
            for (int n = 0; n < 4; ++n)
#pragma unroll
                for (int reg = 0; reg < 4; ++reg) {
                    const int row = row0 + wy * 64 + m * 16 + quad * 4 + reg;
                    const int col = col0 + wx * 64 + n * 16 + r16;
                    _Float16 hb = (_Float16)acc[m][n][reg];
                    Vh[row * DIM + col] = *(u16*)&hb;
                }
    }
}

// ---------------- filter: S = Yh @ Xh^T (fp16), per-64col-group margin emit ----
__global__ __launch_bounds__(256) void filter_kernel(const u16* __restrict__ Yhp,
                                                     const u16* __restrict__ Xhp,
                                                     int* __restrict__ cnt,
                                                     int2* __restrict__ cand) {
    __shared__ short Ls[4][2][4096];
    const int tid = threadIdx.x, w = tid >> 6, lane = tid & 63;
    const int wy = w >> 1, wx = w & 1, quad = lane >> 4, r16 = lane & 15;
    const int id = blockIdx.x;
    const int colt = id >> 6;              // 0..63 ; id%8 == rowt%8 (XCD pin)
    const int rowt = id & 63;              // 0..63
    const int row0 = rowt * 128, col0 = colt * 128;

    const u16* const Ap[1] = { Yhp };
    const u16* const Bp[1] = { Xhp };
    f32x4 acc[4][4] = {};
    gemm_wp<1>(Ap, Bp, row0, col0, acc, Ls[w]);

    // per row: 64-col group max -> margin filter -> emit (mechanics proven R2-R8)
#pragma unroll
    for (int m = 0; m < 4; ++m) {
#pragma unroll
        for (int reg = 0; reg < 4; ++reg) {
            float mx = fmaxf(fmaxf(acc[m][0][reg], acc[m][1][reg]),
                             fmaxf(acc[m][2][reg], acc[m][3][reg]));
            mx = fmaxf(mx, __shfl_xor(mx, 1, 64));
            mx = fmaxf(mx, __shfl_xor(mx, 2, 64));
            mx = fmaxf(mx, __shfl_xor(mx, 4, 64));
            mx = fmaxf(mx, __shfl_xor(mx, 8, 64));
            const float th = mx - MARGIN;
            const int row = row0 + wy * 64 + m * 16 + quad * 4 + reg;
#pragma unroll
            for (int n = 0; n < 4; ++n) {
                float s = acc[m][n][reg];
                if (s >= th) {
                    int pos = atomicAdd(&cnt[row], 1);
                    if (pos < CAP)
                        cand[(size_t)row * CAP + pos] =
                            make_int2(col0 + wx * 64 + n * 16 + r16, __float_as_int(s));
                }
            }
        }
    }
}

// ---------------- finalize: refilter, fp64 rescore via Y·X, softmax, gather Vh -
__global__ __launch_bounds__(256) void finalize_kernel(const float* __restrict__ Y,
                                                       const float* __restrict__ X,
                                                       const u16* __restrict__ Vh,
                                                       const int* __restrict__ cnt,
                                                       const int2* __restrict__ cand,
                                                       float* __restrict__ out) {
    const int i = blockIdx.x;
    const int tid = threadIdx.x;
    const int w = tid >> 6, lane = tid & 63;
    __shared__ float  red[256];
    __shared__ int    surv[64];
    __shared__ double sprec[64];
    __shared__ float  wgt[64];
    __shared__ int    nsurv;

    const int c = min(cnt[i], CAP);
    float m = -3.0e38f;
    for (int t = tid; t < c; t += 256)
        m = fmaxf(m, __int_as_float(cand[(size_t)i * CAP + t].y));
    red[tid] = m;
    __syncthreads();
    for (int s = 128; s > 0; s >>= 1) {
        if (tid < s) red[tid] = fmaxf(red[tid], red[tid + s]);
        __syncthreads();
    }
    const float th = red[0] - MARGIN;
    if (tid == 0) nsurv = 0;
    __syncthreads();
    for (int t = tid; t < c; t += 256) {
        int2 e = cand[(size_t)i * CAP + t];
        if (__int_as_float(e.y) >= th) {
            int p = atomicAdd(&nsurv, 1);
            if (p < 64) surv[p] = e.x;
        }
    }
    __syncthreads();
    const int ns = min(nsurv, 64);
    for (int u = w; u < ns; u += 4) {
        const int j = surv[u];
        double a = 0.0;
        for (int d = lane; d < DIM; d += 64)
            a += (double)Y[(size_t)i * DIM + d] * (double)X[(size_t)j * DIM + d];
#pragma unroll
        for (int o = 32; o > 0; o >>= 1)
            a += __shfl_down(a, o, 64);
        if (lane == 0) sprec[u] = a;
    }
    __syncthreads();
    if (tid == 0) {
        double mm = -1.0e300;
        for (int u = 0; u < ns; ++u) mm = fmax(mm, sprec[u]);
        double l = 0.0;
        for (int u = 0; u < ns; ++u) l += exp(sprec[u] - mm);
        for (int u = 0; u < ns; ++u) wgt[u] = (float)(exp(sprec[u] - mm) / l);
    }
    __syncthreads();
    for (int d = tid; d < DIM; d += 256) {
        float o = 0.f;
        for (int u = 0; u < ns; ++u) {
            _Float16 hv = *(const _Float16*)&Vh[(size_t)surv[u] * DIM + d];
            o += wgt[u] * (float)hv;
        }
        out[(size_t)i * DIM + d] = o;
    }
}

extern "C" void kernel_launch(void* const* d_in, const int* in_sizes, int n_in,
                              void* d_out, int out_size, void* d_ws, size_t ws_size,
                              hipStream_t stream) {
    const float* X  = (const float*)d_in[0];
    const float* wq = (const float*)d_in[1];
    const float* wk = (const float*)d_in[2];
    const float* wv = (const float*)d_in[3];
    float* out = (float*)d_out;

    char* ws = (char*)d_ws;
    const size_t MB = 1024 * 1024;
    u16*   Xh   = (u16*)(ws +   0 * MB);   // 16 MB
    u16*   Xl   = (u16*)(ws +  16 * MB);   // 16 MB
    u16*   Wqh  = (u16*)(ws +  32 * MB);   // 2 MB each
    u16*   Wql  = (u16*)(ws +  34 * MB);
    u16*   Wkh  = (u16*)(ws +  36 * MB);
    u16*   Wkl  = (u16*)(ws +  38 * MB);
    u16*   Wvth = (u16*)(ws +  40 * MB);
    float* Gt   = (float*)(ws + 42 * MB);  // 4 MB fp32 [c][d]
    u16*   Gth  = (u16*)(ws +  46 * MB);
    u16*   Gtl  = (u16*)(ws +  48 * MB);
    float* Y    = (float*)(ws + 64 * MB);  // 32 MB
    u16*   Yh   = (u16*)(ws +  96 * MB);   // 16 MB
    u16*   Vh   = (u16*)(ws + 112 * MB);   // 16 MB
    int*   cnt  = (int*)(ws + 128 * MB);   // 32 KB
    int2*  cand = (int2*)(ws + 129 * MB);  // 8192*256*8 = 16.8 MB

    hipMemsetAsync(cnt, 0, (size_t)NROWS * 4, stream);

    split2h<<<NROWS * DIM / 1024, 256, 0, stream>>>(X, Xh, Xl);
    split2h<<<DIM * DIM / 1024, 256, 0, stream>>>(wq, Wqh, Wql);
    split2h<<<DIM * DIM / 1024, 256, 0, stream>>>(wk, Wkh, Wkl);
    split_wvt<<<dim3(16, 16), 256, 0, stream>>>(wv, Wvth);

    g_gemm<<<dim3(8, 8), 256, 0, stream>>>(Wkh, Wkl, Wqh, Wql, Gt);
    split2h<<<DIM * DIM / 1024, 256, 0, stream>>>(Gt, Gth, Gtl);

    yv_gemm<<<1024, 256, 0, stream>>>(Xh, Xl, Gth, Gtl, Wvth, Y, Yh, Vh);

    filter_kernel<<<4096, 256, 0, stream>>>(Yh, Xh, cnt, cand);

    finalize_kernel<<<NROWS, 256, 0, stream>>>(Y, X, Vh, cnt, cand, out);
}